// Round 5
// baseline (307.022 us; speedup 1.0000x reference)
//
#include <hip/hip_runtime.h>
#include <hip/hip_bf16.h>

// LinearAttention: B=8, N=4096, D=256, HW=N.
// Pipeline (all bf16 MFMA, fp32 accum):
//  q_bf  = bf16(query)                  [32768][256]
//  kv_bf = bf16(key_value^T per batch)  [32768][256]
//  Qb = elu(q_bf @ Wq^T + bq)+1 ; Kb likewise ; Vb = kv_bf @ Wv^T + bv
//  den[b,n] = rowsum(Qb)*rowsum(Kb)
//  KVT[b][d][c] = sum_m Kb[b,m,c]*Vb[b,m,d]   (split-K + fp32 atomics)
//  outb = (Qb @ KV) / (den+1e-6)
//  d_out = outb @ Wo^T + bo   (fp32)

typedef __attribute__((ext_vector_type(8))) __bf16 bf16x8;
typedef __attribute__((ext_vector_type(4))) float f32x4;
typedef __attribute__((ext_vector_type(4))) unsigned short u16x4;
typedef __attribute__((ext_vector_type(8))) unsigned short u16x8;

#define DEVI __device__ __forceinline__

static constexpr int BATCH = 8;
static constexpr int NTOK  = 4096;
static constexpr int DDIM  = 256;

DEVI float bf2f(unsigned short u) {
  union { float f; unsigned int i; } x; x.i = ((unsigned int)u) << 16; return x.f;
}
DEVI unsigned short f2bf(float f) {
  union { float f; unsigned int i; } x; x.f = f;
  unsigned int r = x.i + 0x7fffu + ((x.i >> 16) & 1u);
  return (unsigned short)(r >> 16);
}

// ---------- conversion kernels ----------
__global__ __launch_bounds__(256) void conv_q_kernel(const float* __restrict__ src,
                                                     unsigned short* __restrict__ dst) {
  size_t base = ((size_t)blockIdx.x * 256 + threadIdx.x) * 16;
#pragma unroll
  for (int j = 0; j < 4; ++j) {
    float4 v = *reinterpret_cast<const float4*>(src + base + j * 4);
    u16x4 o = { f2bf(v.x), f2bf(v.y), f2bf(v.z), f2bf(v.w) };
    *reinterpret_cast<u16x4*>(dst + base + j * 4) = o;
  }
}

__global__ __launch_bounds__(256) void conv_w_kernel(const float* __restrict__ w0, const float* __restrict__ w1,
                                                     const float* __restrict__ w2, const float* __restrict__ w3,
                                                     unsigned short* __restrict__ o0, unsigned short* __restrict__ o1,
                                                     unsigned short* __restrict__ o2, unsigned short* __restrict__ o3) {
  size_t i = ((size_t)blockIdx.x * 256 + threadIdx.x) * 4;
  float4 a = *reinterpret_cast<const float4*>(w0 + i);
  float4 b = *reinterpret_cast<const float4*>(w1 + i);
  float4 c = *reinterpret_cast<const float4*>(w2 + i);
  float4 d = *reinterpret_cast<const float4*>(w3 + i);
  u16x4 oa = { f2bf(a.x), f2bf(a.y), f2bf(a.z), f2bf(a.w) };
  u16x4 ob = { f2bf(b.x), f2bf(b.y), f2bf(b.z), f2bf(b.w) };
  u16x4 oc = { f2bf(c.x), f2bf(c.y), f2bf(c.z), f2bf(c.w) };
  u16x4 od = { f2bf(d.x), f2bf(d.y), f2bf(d.z), f2bf(d.w) };
  *reinterpret_cast<u16x4*>(o0 + i) = oa;
  *reinterpret_cast<u16x4*>(o1 + i) = ob;
  *reinterpret_cast<u16x4*>(o2 + i) = oc;
  *reinterpret_cast<u16x4*>(o3 + i) = od;
}

// key_value [B][D][M] fp32 -> kv_bf [B][M][D] bf16
__global__ __launch_bounds__(256) void kv_transpose(const float* __restrict__ src,
                                                    unsigned short* __restrict__ dst) {
  __shared__ float t[32][33];
  int b = blockIdx.z;
  int m0 = blockIdx.x * 32, d0 = blockIdx.y * 32;
  int tx = threadIdx.x, ty = threadIdx.y; // 32 x 8
  const float* s = src + ((size_t)b * DDIM + d0) * NTOK + m0;
#pragma unroll
  for (int i = 0; i < 4; ++i) t[ty + i * 8][tx] = s[(size_t)(ty + i * 8) * NTOK + tx];
  __syncthreads();
  unsigned short* d = dst + ((size_t)b * NTOK + m0) * DDIM + d0;
#pragma unroll
  for (int i = 0; i < 4; ++i) d[(size_t)(ty + i * 8) * DDIM + tx] = f2bf(t[tx][ty + i * 8]);
}

// ---------- projection GEMM: C = act(A @ W^T + bias) ----------
// A [M][256] bf16 row-major, W [256][256] bf16 (row = out col, col = k)
template <int ACT, int OUTF32>
__global__ __launch_bounds__(256) void gemm_proj(const unsigned short* __restrict__ A,
                                                 const unsigned short* __restrict__ W,
                                                 const float* __restrict__ bias,
                                                 void* __restrict__ outp) {
  constexpr int LDT = 72; // padded LDS row stride in u16 (144B: 2-way bank alias, ~free)
  __shared__ unsigned short As[128 * LDT];
  __shared__ unsigned short Ws[128 * LDT];

  const int tid = threadIdx.x;
  const int m0 = blockIdx.x * 128;
  const int c0 = blockIdx.y * 128;
  const int w = tid >> 6, l = tid & 63;
  const int wr = (w >> 1) * 64, wc = (w & 1) * 64;
  const int lr = l & 15, lk = (l >> 4) * 8;

  f32x4 acc[4][4] = {};

  for (int k0 = 0; k0 < 256; k0 += 64) {
#pragma unroll
    for (int it = 0; it < 4; ++it) {
      int idx = tid + it * 256;     // 0..1023
      int r = idx >> 3;             // 0..127
      int c = (idx & 7) * 8;        // 0..56
      *reinterpret_cast<u16x8*>(&As[r * LDT + c]) =
          *reinterpret_cast<const u16x8*>(A + (size_t)(m0 + r) * 256 + k0 + c);
      *reinterpret_cast<u16x8*>(&Ws[r * LDT + c]) =
          *reinterpret_cast<const u16x8*>(W + (size_t)(c0 + r) * 256 + k0 + c);
    }
    __syncthreads();
#pragma unroll
    for (int kk = 0; kk < 2; ++kk) {
      bf16x8 a[4], b[4];
#pragma unroll
      for (int m = 0; m < 4; ++m)
        a[m] = *reinterpret_cast<const bf16x8*>(&As[(wr + m * 16 + lr) * LDT + kk * 32 + lk]);
#pragma unroll
      for (int n = 0; n < 4; ++n)
        b[n] = *reinterpret_cast<const bf16x8*>(&Ws[(wc + n * 16 + lr) * LDT + kk * 32 + lk]);
#pragma unroll
      for (int m = 0; m < 4; ++m)
#pragma unroll
        for (int n = 0; n < 4; ++n)
          acc[m][n] = __builtin_amdgcn_mfma_f32_16x16x32_bf16(a[m], b[n], acc[m][n], 0, 0, 0);
    }
    __syncthreads();
  }

#pragma unroll
  for (int n = 0; n < 4; ++n) {
    const int col = c0 + wc + n * 16 + lr;
    const float bv = bias[col];
#pragma unroll
    for (int m = 0; m < 4; ++m) {
#pragma unroll
      for (int j = 0; j < 4; ++j) {
        int row = m0 + wr + m * 16 + (l >> 4) * 4 + j;
        float x = acc[m][n][j] + bv;
        if (ACT) x = (x > 0.0f) ? (x + 1.0f) : __expf(x);
        if (OUTF32)
          reinterpret_cast<float*>(outp)[(size_t)row * 256 + col] = x;
        else
          reinterpret_cast<unsigned short*>(outp)[(size_t)row * 256 + col] = f2bf(x);
      }
    }
  }
}

// ---------- den[b,n] = rowsum(Qb)*rowsum(Kb) ----------
__global__ __launch_bounds__(256) void den_kernel(const unsigned short* __restrict__ Qb,
                                                  const unsigned short* __restrict__ Kb,
                                                  float* __restrict__ den) {
  int row = blockIdx.x * 4 + (threadIdx.x >> 6);
  int l = threadIdx.x & 63;
  u16x4 q = *reinterpret_cast<const u16x4*>(Qb + (size_t)row * 256 + l * 4);
  u16x4 k = *reinterpret_cast<const u16x4*>(Kb + (size_t)row * 256 + l * 4);
  float qs = bf2f(q[0]) + bf2f(q[1]) + bf2f(q[2]) + bf2f(q[3]);
  float ks = bf2f(k[0]) + bf2f(k[1]) + bf2f(k[2]) + bf2f(k[3]);
#pragma unroll
  for (int s = 32; s > 0; s >>= 1) {
    qs += __shfl_xor(qs, s);
    ks += __shfl_xor(ks, s);
  }
  if (l == 0) den[row] = qs * ks;
}

// ---------- KVT[b][d][c] += sum_m K[b][m][c] * V[b][m][d] ----------
__global__ __launch_bounds__(256) void kv_outer(const unsigned short* __restrict__ Kb,
                                                const unsigned short* __restrict__ Vb,
                                                float* __restrict__ KVT) {
  constexpr int LDT = 72;
  __shared__ unsigned short Ks[128 * LDT]; // [c][m] transposed
  __shared__ unsigned short Vs[128 * LDT]; // [d][m] transposed
  const int tid = threadIdx.x;
  const int b = blockIdx.z;
  const int c0 = (blockIdx.x >> 1) * 128;
  const int d0 = (blockIdx.x & 1) * 128;
  const int msplit = blockIdx.y * 512;
  const size_t base = (size_t)b * NTOK;

  const int w = tid >> 6, l = tid & 63;
  const int wr = (w >> 1) * 64, wc = (w & 1) * 64;
  const int lr = l & 15, lk = (l >> 4) * 8;

  f32x4 acc[4][4] = {};

  for (int kt = 0; kt < 8; ++kt) {
    int ms = msplit + kt * 64;
#pragma unroll
    for (int it = 0; it < 4; ++it) {
      int idx = tid + it * 256;   // 0..1023
      int m = idx >> 4;           // 0..63
      int c = (idx & 15) * 8;     // 0..120
      u16x8 kv = *reinterpret_cast<const u16x8*>(Kb + (base + ms + m) * 256 + c0 + c);
      u16x8 vv = *reinterpret_cast<const u16x8*>(Vb + (base + ms + m) * 256 + d0 + c);
#pragma unroll
      for (int i = 0; i < 8; ++i) {
        Ks[(c + i) * LDT + m] = kv[i];
        Vs[(c + i) * LDT + m] = vv[i];
      }
    }
    __syncthreads();
#pragma unroll
    for (int kk = 0; kk < 2; ++kk) {
      bf16x8 a[4], bb[4];
#pragma unroll
      for (int m = 0; m < 4; ++m)
        a[m] = *reinterpret_cast<const bf16x8*>(&Ks[(wr + m * 16 + lr) * LDT + kk * 32 + lk]);
#pragma unroll
      for (int n = 0; n < 4; ++n)
        bb[n] = *reinterpret_cast<const bf16x8*>(&Vs[(wc + n * 16 + lr) * LDT + kk * 32 + lk]);
#pragma unroll
      for (int m = 0; m < 4; ++m)
#pragma unroll
        for (int n = 0; n < 4; ++n)
          acc[m][n] = __builtin_amdgcn_mfma_f32_16x16x32_bf16(a[m], bb[n], acc[m][n], 0, 0, 0);
    }
    __syncthreads();
  }

#pragma unroll
  for (int n = 0; n < 4; ++n) {
    int d = d0 + wc + n * 16 + lr;
#pragma unroll
    for (int m = 0; m < 4; ++m) {
#pragma unroll
      for (int j = 0; j < 4; ++j) {
        int c = c0 + wr + m * 16 + (l >> 4) * 4 + j;
        atomicAdd(&KVT[((size_t)b * 256 + d) * 256 + c], acc[m][n][j]);
      }
    }
  }
}

// ---------- outb = (Qb @ KV) / (den + 1e-6) ----------
__global__ __launch_bounds__(256) void gemm_num(const unsigned short* __restrict__ Qb,
                                                const float* __restrict__ KVT,
                                                const float* __restrict__ den,
                                                unsigned short* __restrict__ outb) {
  constexpr int LDT = 72;
  __shared__ unsigned short As[128 * LDT];
  __shared__ unsigned short Bs[128 * LDT]; // [d][c] bf16 (from fp32 KVT)
  const int tid = threadIdx.x;
  const int b = blockIdx.z;
  const int m0 = blockIdx.x * 128;
  const int d0 = blockIdx.y * 128;
  const size_t abase = (size_t)b * NTOK;

  const int w = tid >> 6, l = tid & 63;
  const int wr = (w >> 1) * 64, wc = (w & 1) * 64;
  const int lr = l & 15, lk = (l >> 4) * 8;

  f32x4 acc[4][4] = {};

  for (int k0 = 0; k0 < 256; k0 += 64) {
#pragma unroll
    for (int it = 0; it < 4; ++it) {
      int idx = tid + it * 256;
      int r = idx >> 3, c = (idx & 7) * 8;
      *reinterpret_cast<u16x8*>(&As[r * LDT + c]) =
          *reinterpret_cast<const u16x8*>(Qb + (abase + m0 + r) * 256 + k0 + c);
    }
#pragma unroll
    for (int it = 0; it < 8; ++it) {
      int idx = tid + it * 256;    // 0..2047
      int dl = idx >> 4;           // 0..127
      int cl = (idx & 15) * 4;     // 0..60
      float4 v = *reinterpret_cast<const float4*>(KVT + ((size_t)b * 256 + d0 + dl) * 256 + k0 + cl);
      u16x4 o = { f2bf(v.x), f2bf(v.y), f2bf(v.z), f2bf(v.w) };
      *reinterpret_cast<u16x4*>(&Bs[dl * LDT + cl]) = o;
    }
    __syncthreads();
#pragma unroll
    for (int kk = 0; kk < 2; ++kk) {
      bf16x8 a[4], bb[4];
#pragma unroll
      for (int m = 0; m < 4; ++m)
        a[m] = *reinterpret_cast<const bf16x8*>(&As[(wr + m * 16 + lr) * LDT + kk * 32 + lk]);
#pragma unroll
      for (int n = 0; n < 4; ++n)
        bb[n] = *reinterpret_cast<const bf16x8*>(&Bs[(wc + n * 16 + lr) * LDT + kk * 32 + lk]);
#pragma unroll
      for (int m = 0; m < 4; ++m)
#pragma unroll
        for (int n = 0; n < 4; ++n)
          acc[m][n] = __builtin_amdgcn_mfma_f32_16x16x32_bf16(a[m], bb[n], acc[m][n], 0, 0, 0);
    }
    __syncthreads();
  }

#pragma unroll
  for (int n = 0; n < 4; ++n) {
    int col = d0 + wc + n * 16 + lr;
#pragma unroll
    for (int m = 0; m < 4; ++m) {
#pragma unroll
      for (int j = 0; j < 4; ++j) {
        int row = m0 + wr + m * 16 + (l >> 4) * 4 + j;
        float dv = den[abase + row] + 1e-6f;
        outb[(abase + row) * 256 + col] = f2bf(acc[m][n][j] / dv);
      }
    }
  }
}

extern "C" void kernel_launch(void* const* d_in, const int* in_sizes, int n_in,
                              void* d_out, int out_size, void* d_ws, size_t ws_size,
                              hipStream_t stream) {
  const float* query     = (const float*)d_in[0];
  const float* key_value = (const float*)d_in[1];
  const float* Wq = (const float*)d_in[2];
  const float* bq = (const float*)d_in[3];
  const float* Wk = (const float*)d_in[4];
  const float* bk = (const float*)d_in[5];
  const float* Wv = (const float*)d_in[6];
  const float* bv = (const float*)d_in[7];
  const float* Wo = (const float*)d_in[8];
  const float* bo = (const float*)d_in[9];

  char* ws = (char*)d_ws;
  const size_t MB = 1ull << 20;
  unsigned short* q_bf  = (unsigned short*)(ws + 0 * MB);   // 16MB, reused as outb
  unsigned short* kv_bf = (unsigned short*)(ws + 16 * MB);  // 16MB
  unsigned short* Qb    = (unsigned short*)(ws + 32 * MB);  // 16MB
  unsigned short* Kb    = (unsigned short*)(ws + 48 * MB);  // 16MB
  unsigned short* Vb    = (unsigned short*)(ws + 64 * MB);  // 16MB
  float* KVT            = (float*)(ws + 80 * MB);           // 2MB
  float* den            = (float*)(ws + 82 * MB);           // 128KB
  unsigned short* wqb   = (unsigned short*)(ws + 82 * MB + 128 * 1024);
  unsigned short* wkb   = (unsigned short*)(ws + 82 * MB + 256 * 1024);
  unsigned short* wvb   = (unsigned short*)(ws + 82 * MB + 384 * 1024);
  unsigned short* wob   = (unsigned short*)(ws + 82 * MB + 512 * 1024);
  unsigned short* outb  = q_bf;

  hipMemsetAsync(KVT, 0, (size_t)BATCH * 256 * 256 * sizeof(float), stream);

  conv_q_kernel<<<2048, 256, 0, stream>>>(query, q_bf);
  conv_w_kernel<<<64, 256, 0, stream>>>(Wq, Wk, Wv, Wo, wqb, wkb, wvb, wob);
  kv_transpose<<<dim3(128, 8, 8), dim3(32, 8), 0, stream>>>(key_value, kv_bf);

  gemm_proj<1, 0><<<dim3(256, 2), 256, 0, stream>>>(q_bf, wqb, bq, Qb);
  gemm_proj<1, 0><<<dim3(256, 2), 256, 0, stream>>>(kv_bf, wkb, bk, Kb);
  gemm_proj<0, 0><<<dim3(256, 2), 256, 0, stream>>>(kv_bf, wvb, bv, Vb);

  den_kernel<<<8192, 256, 0, stream>>>(Qb, Kb, den);
  kv_outer<<<dim3(4, 8, 8), 256, 0, stream>>>(Kb, Vb, KVT);
  gemm_num<<<dim3(32, 2, 8), 256, 0, stream>>>(Qb, KVT, den, outb);
  gemm_proj<0, 1><<<dim3(256, 2), 256, 0, stream>>>(outb, wob, bo, d_out);
}

// Round 8
// 255.317 us; speedup vs baseline: 1.2025x; 1.2025x over previous
//
#include <hip/hip_runtime.h>
#include <hip/hip_bf16.h>

// LinearAttention: B=8, N=4096, D=256, HW=N.
// Pipeline (all bf16 MFMA, fp32 accum):
//  q_bf  = bf16(query); kv_bf = bf16(key_value^T per batch)
//  Qb = elu(q_bf@Wq^T+bq)+1 ; Kb likewise ; Vb = kv_bf@Wv^T+bv
//  Kt[b][c][m] = Kb^T, Vt[b][d][m] = Vb^T        (global transpose, HBM-bound)
//  KVT[b][d][c] = sum_m Kb[m,c]*Vb[m,d]          (plain GEMM on Vt,Kt; split-K partials + reduce)
//  den[b,n] = rowsum(Qb)*rowsum(Kb)
//  outb = (Qb @ KV) / (den+1e-6);  d_out = outb @ Wo^T + bo (fp32)

typedef __attribute__((ext_vector_type(8))) __bf16 bf16x8;
typedef __attribute__((ext_vector_type(4))) float f32x4;
typedef __attribute__((ext_vector_type(4))) unsigned short u16x4;
typedef __attribute__((ext_vector_type(8))) unsigned short u16x8;

#define DEVI __device__ __forceinline__

static constexpr int BATCH = 8;
static constexpr int NTOK  = 4096;
static constexpr int DDIM  = 256;

DEVI float bf2f(unsigned short u) {
  union { float f; unsigned int i; } x; x.i = ((unsigned int)u) << 16; return x.f;
}
DEVI unsigned short f2bf(float f) {
  union { float f; unsigned int i; } x; x.f = f;
  unsigned int r = x.i + 0x7fffu + ((x.i >> 16) & 1u);
  return (unsigned short)(r >> 16);
}

// ---------- conversion kernels ----------
__global__ __launch_bounds__(256) void conv_q_kernel(const float* __restrict__ src,
                                                     unsigned short* __restrict__ dst) {
  size_t base = ((size_t)blockIdx.x * 256 + threadIdx.x) * 16;
#pragma unroll
  for (int j = 0; j < 4; ++j) {
    float4 v = *reinterpret_cast<const float4*>(src + base + j * 4);
    u16x4 o = { f2bf(v.x), f2bf(v.y), f2bf(v.z), f2bf(v.w) };
    *reinterpret_cast<u16x4*>(dst + base + j * 4) = o;
  }
}

__global__ __launch_bounds__(256) void conv_w_kernel(const float* __restrict__ w0, const float* __restrict__ w1,
                                                     const float* __restrict__ w2, const float* __restrict__ w3,
                                                     unsigned short* __restrict__ o0, unsigned short* __restrict__ o1,
                                                     unsigned short* __restrict__ o2, unsigned short* __restrict__ o3) {
  size_t i = ((size_t)blockIdx.x * 256 + threadIdx.x) * 4;
  float4 a = *reinterpret_cast<const float4*>(w0 + i);
  float4 b = *reinterpret_cast<const float4*>(w1 + i);
  float4 c = *reinterpret_cast<const float4*>(w2 + i);
  float4 d = *reinterpret_cast<const float4*>(w3 + i);
  u16x4 oa = { f2bf(a.x), f2bf(a.y), f2bf(a.z), f2bf(a.w) };
  u16x4 ob = { f2bf(b.x), f2bf(b.y), f2bf(b.z), f2bf(b.w) };
  u16x4 oc = { f2bf(c.x), f2bf(c.y), f2bf(c.z), f2bf(c.w) };
  u16x4 od = { f2bf(d.x), f2bf(d.y), f2bf(d.z), f2bf(d.w) };
  *reinterpret_cast<u16x4*>(o0 + i) = oa;
  *reinterpret_cast<u16x4*>(o1 + i) = ob;
  *reinterpret_cast<u16x4*>(o2 + i) = oc;
  *reinterpret_cast<u16x4*>(o3 + i) = od;
}

// key_value [B][D][M] fp32 -> kv_bf [B][M][D] bf16
__global__ __launch_bounds__(256) void kv_transpose(const float* __restrict__ src,
                                                    unsigned short* __restrict__ dst) {
  __shared__ float t[32][33];
  int b = blockIdx.z;
  int m0 = blockIdx.x * 32, d0 = blockIdx.y * 32;
  int tx = threadIdx.x, ty = threadIdx.y; // 32 x 8
  const float* s = src + ((size_t)b * DDIM + d0) * NTOK + m0;
#pragma unroll
  for (int i = 0; i < 4; ++i) t[ty + i * 8][tx] = s[(size_t)(ty + i * 8) * NTOK + tx];
  __syncthreads();
  unsigned short* d = dst + ((size_t)b * NTOK + m0) * DDIM + d0;
#pragma unroll
  for (int i = 0; i < 4; ++i) d[(size_t)(ty + i * 8) * DDIM + tx] = f2bf(t[tx][ty + i * 8]);
}

// bf16 [B][4096][256] -> bf16 [B][256][4096]  (64x64 tiles, vectorized both sides)
__global__ __launch_bounds__(256) void t64_kernel(const unsigned short* __restrict__ src,
                                                  unsigned short* __restrict__ dst) {
  constexpr int LDT = 68; // u16 row stride: b64-aligned writes, despread column reads
  __shared__ unsigned short Ts[64 * LDT];
  const int tid = threadIdx.x;
  const int b = blockIdx.z;
  const int m0 = blockIdx.x * 64;  // 0..4032
  const int c0 = blockIdx.y * 64;  // 0..192
  // phase 1: read [m][c] coalesced (u16x4 = 8B/lane), write LDS rows
  {
    const int cg = tid & 15;        // 16 col-groups of 4
    const int rb = tid >> 4;        // 16 rows per iter
#pragma unroll
    for (int it = 0; it < 4; ++it) {
      int r = rb + it * 16;
      u16x4 v = *reinterpret_cast<const u16x4*>(src + ((size_t)b * NTOK + m0 + r) * 256 + c0 + cg * 4);
      *reinterpret_cast<u16x4*>(&Ts[r * LDT + cg * 4]) = v;
    }
  }
  __syncthreads();
  // phase 2: read LDS columns (scalar), write [c][m] coalesced (2x u16x8 = 32B/lane)
  {
    const int c = tid >> 2;         // 0..63
    const int mg = tid & 3;         // 4 m-groups of 16
    u16x8 o0, o1;
#pragma unroll
    for (int j = 0; j < 8; ++j) o0[j] = Ts[(mg * 16 + j) * LDT + c];
#pragma unroll
    for (int j = 0; j < 8; ++j) o1[j] = Ts[(mg * 16 + 8 + j) * LDT + c];
    unsigned short* d = dst + ((size_t)b * DDIM + c0 + c) * NTOK + m0 + mg * 16;
    *reinterpret_cast<u16x8*>(d) = o0;
    *reinterpret_cast<u16x8*>(d + 8) = o1;
  }
}

// ---------- projection GEMM: C = act(A @ W^T + bias) ----------
template <int ACT, int OUTF32>
__global__ __launch_bounds__(256) void gemm_proj(const unsigned short* __restrict__ A,
                                                 const unsigned short* __restrict__ W,
                                                 const float* __restrict__ bias,
                                                 void* __restrict__ outp) {
  constexpr int LDT = 72;
  __shared__ unsigned short As[128 * LDT];
  __shared__ unsigned short Ws[128 * LDT];

  const int tid = threadIdx.x;
  const int m0 = blockIdx.x * 128;
  const int c0 = blockIdx.y * 128;
  const int w = tid >> 6, l = tid & 63;
  const int wr = (w >> 1) * 64, wc = (w & 1) * 64;
  const int lr = l & 15, lk = (l >> 4) * 8;

  f32x4 acc[4][4] = {};

  for (int k0 = 0; k0 < 256; k0 += 64) {
#pragma unroll
    for (int it = 0; it < 4; ++it) {
      int idx = tid + it * 256;
      int r = idx >> 3;
      int c = (idx & 7) * 8;
      *reinterpret_cast<u16x8*>(&As[r * LDT + c]) =
          *reinterpret_cast<const u16x8*>(A + (size_t)(m0 + r) * 256 + k0 + c);
      *reinterpret_cast<u16x8*>(&Ws[r * LDT + c]) =
          *reinterpret_cast<const u16x8*>(W + (size_t)(c0 + r) * 256 + k0 + c);
    }
    __syncthreads();
#pragma unroll
    for (int kk = 0; kk < 2; ++kk) {
      bf16x8 a[4], b[4];
#pragma unroll
      for (int m = 0; m < 4; ++m)
        a[m] = *reinterpret_cast<const bf16x8*>(&As[(wr + m * 16 + lr) * LDT + kk * 32 + lk]);
#pragma unroll
      for (int n = 0; n < 4; ++n)
        b[n] = *reinterpret_cast<const bf16x8*>(&Ws[(wc + n * 16 + lr) * LDT + kk * 32 + lk]);
#pragma unroll
      for (int m = 0; m < 4; ++m)
#pragma unroll
        for (int n = 0; n < 4; ++n)
          acc[m][n] = __builtin_amdgcn_mfma_f32_16x16x32_bf16(a[m], b[n], acc[m][n], 0, 0, 0);
    }
    __syncthreads();
  }

#pragma unroll
  for (int n = 0; n < 4; ++n) {
    const int col = c0 + wc + n * 16 + lr;
    const float bv = bias[col];
#pragma unroll
    for (int m = 0; m < 4; ++m) {
#pragma unroll
      for (int j = 0; j < 4; ++j) {
        int row = m0 + wr + m * 16 + (l >> 4) * 4 + j;
        float x = acc[m][n][j] + bv;
        if (ACT) x = (x > 0.0f) ? (x + 1.0f) : __expf(x);
        if (OUTF32)
          reinterpret_cast<float*>(outp)[(size_t)row * 256 + col] = x;
        else
          reinterpret_cast<unsigned short*>(outp)[(size_t)row * 256 + col] = f2bf(x);
      }
    }
  }
}

// ---------- den[b,n] = rowsum(Qb)*rowsum(Kb) ----------
__global__ __launch_bounds__(256) void den_kernel(const unsigned short* __restrict__ Qb,
                                                  const unsigned short* __restrict__ Kb,
                                                  float* __restrict__ den) {
  int row = blockIdx.x * 4 + (threadIdx.x >> 6);
  int l = threadIdx.x & 63;
  u16x4 q = *reinterpret_cast<const u16x4*>(Qb + (size_t)row * 256 + l * 4);
  u16x4 k = *reinterpret_cast<const u16x4*>(Kb + (size_t)row * 256 + l * 4);
  float qs = bf2f(q[0]) + bf2f(q[1]) + bf2f(q[2]) + bf2f(q[3]);
  float ks = bf2f(k[0]) + bf2f(k[1]) + bf2f(k[2]) + bf2f(k[3]);
#pragma unroll
  for (int s = 32; s > 0; s >>= 1) {
    qs += __shfl_xor(qs, s);
    ks += __shfl_xor(ks, s);
  }
  if (l == 0) den[row] = qs * ks;
}

// ---------- KVT partials: plain GEMM, A=Vt rows(d), B=Kt rows(c), k=m ----------
// partial[s][b][d][c] = sum_{m in split s} Vt[b][d][m] * Kt[b][c][m]
__global__ __launch_bounds__(256) void kv_gemm(const unsigned short* __restrict__ Vt,
                                               const unsigned short* __restrict__ Kt,
                                               float* __restrict__ partial) {
  constexpr int LDT = 72;
  __shared__ unsigned short As[128 * LDT]; // Vt rows (d)
  __shared__ unsigned short Bs[128 * LDT]; // Kt rows (c)
  const int tid = threadIdx.x;
  const int b = blockIdx.z;
  const int s = blockIdx.y;
  const int c0 = (blockIdx.x & 1) * 128;
  const int d0 = (blockIdx.x >> 1) * 128;
  const int ms = s * 512;

  const int w = tid >> 6, l = tid & 63;
  const int wr = (w >> 1) * 64, wc = (w & 1) * 64;
  const int lr = l & 15, lk = (l >> 4) * 8;

  const size_t vbase = ((size_t)b * DDIM + d0) * NTOK;
  const size_t kbase = ((size_t)b * DDIM + c0) * NTOK;

  f32x4 acc[4][4] = {};

  for (int mc = 0; mc < 512; mc += 64) {
#pragma unroll
    for (int it = 0; it < 4; ++it) {
      int idx = tid + it * 256;
      int r = idx >> 3;
      int kg = (idx & 7) * 8;
      *reinterpret_cast<u16x8*>(&As[r * LDT + kg]) =
          *reinterpret_cast<const u16x8*>(Vt + vbase + (size_t)r * NTOK + ms + mc + kg);
      *reinterpret_cast<u16x8*>(&Bs[r * LDT + kg]) =
          *reinterpret_cast<const u16x8*>(Kt + kbase + (size_t)r * NTOK + ms + mc + kg);
    }
    __syncthreads();
#pragma unroll
    for (int kk = 0; kk < 2; ++kk) {
      bf16x8 a[4], bb[4];
#pragma unroll
      for (int m = 0; m < 4; ++m)
        a[m] = *reinterpret_cast<const bf16x8*>(&As[(wr + m * 16 + lr) * LDT + kk * 32 + lk]);
#pragma unroll
      for (int n = 0; n < 4; ++n)
        bb[n] = *reinterpret_cast<const bf16x8*>(&Bs[(wc + n * 16 + lr) * LDT + kk * 32 + lk]);
#pragma unroll
      for (int m = 0; m < 4; ++m)
#pragma unroll
        for (int n = 0; n < 4; ++n)
          acc[m][n] = __builtin_amdgcn_mfma_f32_16x16x32_bf16(a[m], bb[n], acc[m][n], 0, 0, 0);
    }
    __syncthreads();
  }

  float* p = partial + (size_t)(s * BATCH + b) * 65536;
#pragma unroll
  for (int n = 0; n < 4; ++n) {
    int c = c0 + wc + n * 16 + lr;
#pragma unroll
    for (int m = 0; m < 4; ++m) {
#pragma unroll
      for (int j = 0; j < 4; ++j) {
        int d = d0 + wr + m * 16 + (l >> 4) * 4 + j;
        p[(size_t)d * 256 + c] = acc[m][n][j];
      }
    }
  }
}

// ---------- KVT[b][d][c] = sum_s partial[s][b][d][c] ----------
__global__ __launch_bounds__(256) void kv_reduce(const float* __restrict__ partial,
                                                 float* __restrict__ KVT) {
  size_t i = ((size_t)blockIdx.x * 256 + threadIdx.x) * 4;
  float4 acc = *reinterpret_cast<const float4*>(partial + i);
#pragma unroll
  for (int s = 1; s < 8; ++s) {
    float4 v = *reinterpret_cast<const float4*>(partial + (size_t)s * 524288 + i);
    acc.x += v.x; acc.y += v.y; acc.z += v.z; acc.w += v.w;
  }
  *reinterpret_cast<float4*>(KVT + i) = acc;
}

// ---------- outb = (Qb @ KV) / (den + 1e-6) ----------
__global__ __launch_bounds__(256) void gemm_num(const unsigned short* __restrict__ Qb,
                                                const float* __restrict__ KVT,
                                                const float* __restrict__ den,
                                                unsigned short* __restrict__ outb) {
  constexpr int LDT = 72;
  __shared__ unsigned short As[128 * LDT];
  __shared__ unsigned short Bs[128 * LDT];
  const int tid = threadIdx.x;
  const int b = blockIdx.z;
  const int m0 = blockIdx.x * 128;
  const int d0 = blockIdx.y * 128;
  const size_t abase = (size_t)b * NTOK;

  const int w = tid >> 6, l = tid & 63;
  const int wr = (w >> 1) * 64, wc = (w & 1) * 64;
  const int lr = l & 15, lk = (l >> 4) * 8;

  f32x4 acc[4][4] = {};

  for (int k0 = 0; k0 < 256; k0 += 64) {
#pragma unroll
    for (int it = 0; it < 4; ++it) {
      int idx = tid + it * 256;
      int r = idx >> 3, c = (idx & 7) * 8;
      *reinterpret_cast<u16x8*>(&As[r * LDT + c]) =
          *reinterpret_cast<const u16x8*>(Qb + (abase + m0 + r) * 256 + k0 + c);
    }
#pragma unroll
    for (int it = 0; it < 8; ++it) {
      int idx = tid + it * 256;
      int dl = idx >> 4;
      int cl = (idx & 15) * 4;
      float4 v = *reinterpret_cast<const float4*>(KVT + ((size_t)b * 256 + d0 + dl) * 256 + k0 + cl);
      u16x4 o = { f2bf(v.x), f2bf(v.y), f2bf(v.z), f2bf(v.w) };
      *reinterpret_cast<u16x4*>(&Bs[dl * LDT + cl]) = o;
    }
    __syncthreads();
#pragma unroll
    for (int kk = 0; kk < 2; ++kk) {
      bf16x8 a[4], bb[4];
#pragma unroll
      for (int m = 0; m < 4; ++m)
        a[m] = *reinterpret_cast<const bf16x8*>(&As[(wr + m * 16 + lr) * LDT + kk * 32 + lk]);
#pragma unroll
      for (int n = 0; n < 4; ++n)
        bb[n] = *reinterpret_cast<const bf16x8*>(&Bs[(wc + n * 16 + lr) * LDT + kk * 32 + lk]);
#pragma unroll
      for (int m = 0; m < 4; ++m)
#pragma unroll
        for (int n = 0; n < 4; ++n)
          acc[m][n] = __builtin_amdgcn_mfma_f32_16x16x32_bf16(a[m], bb[n], acc[m][n], 0, 0, 0);
    }
    __syncthreads();
  }

#pragma unroll
  for (int n = 0; n < 4; ++n) {
    int col = d0 + wc + n * 16 + lr;
#pragma unroll
    for (int m = 0; m < 4; ++m) {
#pragma unroll
      for (int j = 0; j < 4; ++j) {
        int row = m0 + wr + m * 16 + (l >> 4) * 4 + j;
        float dv = den[abase + row] + 1e-6f;
        outb[(abase + row) * 256 + col] = f2bf(acc[m][n][j] / dv);
      }
    }
  }
}

extern "C" void kernel_launch(void* const* d_in, const int* in_sizes, int n_in,
                              void* d_out, int out_size, void* d_ws, size_t ws_size,
                              hipStream_t stream) {
  const float* query     = (const float*)d_in[0];
  const float* key_value = (const float*)d_in[1];
  const float* Wq = (const float*)d_in[2];
  const float* bq = (const float*)d_in[3];
  const float* Wk = (const float*)d_in[4];
  const float* bk = (const float*)d_in[5];
  const float* Wv = (const float*)d_in[6];
  const float* bv = (const float*)d_in[7];
  const float* Wo = (const float*)d_in[8];
  const float* bo = (const float*)d_in[9];

  char* ws = (char*)d_ws;
  const size_t MB = 1ull << 20;
  // lifetimes: q_bf dead after projQ -> Kt; kv_bf dead after projV -> Vt;
  // Vb dead after t64(V) -> partial; Kt dead after kv_gemm -> outb.
  unsigned short* q_bf  = (unsigned short*)(ws + 0 * MB);   // 16MB; later Kt, then outb
  unsigned short* kv_bf = (unsigned short*)(ws + 16 * MB);  // 16MB; later Vt
  unsigned short* Qb    = (unsigned short*)(ws + 32 * MB);  // 16MB
  unsigned short* Kb    = (unsigned short*)(ws + 48 * MB);  // 16MB
  unsigned short* Vb    = (unsigned short*)(ws + 64 * MB);  // 16MB; later partial
  float* KVT            = (float*)(ws + 80 * MB);           // 2MB
  float* den            = (float*)(ws + 82 * MB);           // 128KB
  unsigned short* wqb   = (unsigned short*)(ws + 82 * MB + 128 * 1024);
  unsigned short* wkb   = (unsigned short*)(ws + 82 * MB + 256 * 1024);
  unsigned short* wvb   = (unsigned short*)(ws + 82 * MB + 384 * 1024);
  unsigned short* wob   = (unsigned short*)(ws + 82 * MB + 512 * 1024);
  unsigned short* Kt    = q_bf;
  unsigned short* Vt    = kv_bf;
  float* partial        = (float*)(ws + 64 * MB);           // 16MB (8 splits x 2MB)
  unsigned short* outb  = q_bf;

  conv_q_kernel<<<2048, 256, 0, stream>>>(query, q_bf);
  conv_w_kernel<<<64, 256, 0, stream>>>(Wq, Wk, Wv, Wo, wqb, wkb, wvb, wob);
  kv_transpose<<<dim3(128, 8, 8), dim3(32, 8), 0, stream>>>(key_value, kv_bf);

  gemm_proj<1, 0><<<dim3(256, 2), 256, 0, stream>>>(q_bf, wqb, bq, Qb);   // q_bf dead
  gemm_proj<1, 0><<<dim3(256, 2), 256, 0, stream>>>(kv_bf, wkb, bk, Kb);
  gemm_proj<0, 0><<<dim3(256, 2), 256, 0, stream>>>(kv_bf, wvb, bv, Vb);  // kv_bf dead

  t64_kernel<<<dim3(64, 4, 8), 256, 0, stream>>>(Kb, Kt);
  t64_kernel<<<dim3(64, 4, 8), 256, 0, stream>>>(Vb, Vt);                 // Vb dead

  den_kernel<<<8192, 256, 0, stream>>>(Qb, Kb, den);                      // Kb dead
  kv_gemm<<<dim3(4, 8, 8), 256, 0, stream>>>(Vt, Kt, partial);            // Kt,Vt dead after
  kv_reduce<<<512, 256, 0, stream>>>(partial, KVT);                       // partial dead

  gemm_num<<<dim3(32, 2, 8), 256, 0, stream>>>(Qb, KVT, den, outb);
  gemm_proj<0, 1><<<dim3(256, 2), 256, 0, stream>>>(outb, wob, bo, d_out);
}